// Round 9
// baseline (446.999 us; speedup 1.0000x reference)
//
#include <hip/hip_runtime.h>

#define N_NODES 100000
#define N_EDGES 1600000
#define N_GRAPHS 1000
#define HID 128
#define OUTD 6

#define BUCK_LOG 7
#define BUCK_W (1 << BUCK_LOG)                      // 128 nodes per bucket
#define NBUCK ((N_NODES + BUCK_W - 1) >> BUCK_LOG)  // 782
#define BCAP 2560                                    // mean 2048, sigma~45 -> +11 sigma
#define FILL_BLOCKS 512
#define FILL_CHUNK 3128   // multiple of 4; 512*3128 = 1601536 >= N_EDGES

#define CVT_BLOCKS 6250   // 12.8M elems / (8*256)
#define GST_BLOCKS 391
#define PACK_BLOCKS 32
#define PREP_BLOCKS (CVT_BLOCKS + GST_BLOCKS + PACK_BLOCKS + FILL_BLOCKS)

typedef _Float16 h2 __attribute__((ext_vector_type(2)));
typedef _Float16 half8 __attribute__((ext_vector_type(8)));
typedef float f32x4 __attribute__((ext_vector_type(4)));

// ---- fused prep: bucket-fill FIRST (overlaps cvt), x->fp16, gstart, weight pack ----
// Fill: hist pass caches dst chunk in LDS -> scatter pass re-reads dst from LDS
// (one global pass over dstv instead of two).
__global__ __launch_bounds__(256) void k_prep(const float* __restrict__ x,
                                              const int* __restrict__ batch,
                                              const int* __restrict__ srcv,
                                              const int* __restrict__ dstv,
                                              const float* __restrict__ W1a,
                                              const float* __restrict__ W1b,
                                              const float* __restrict__ W2a,
                                              const float* __restrict__ W2b,
                                              _Float16* __restrict__ X16,
                                              int* __restrict__ gstart,
                                              _Float16* __restrict__ P,
                                              int* __restrict__ bcur0,
                                              int* __restrict__ packed) {
    __shared__ int h[NBUCK];
    __shared__ int lcur[NBUCK];
    __shared__ int dcache[FILL_CHUNK];   // 12.5 KB dst chunk cache
    int b = blockIdx.x, t = threadIdx.x;
    if (b < FILL_BLOCKS) {
        // ---- bucket fill (scheduled first: latency-bound, overlaps BW-bound cvt) ----
        // Scatter targets are bucket-contiguous regions -> lines coalesce in L2.
        int e0 = b * FILL_CHUNK;
        int e1 = min(e0 + FILL_CHUNK, N_EDGES);
        for (int i = t; i < NBUCK; i += 256) h[i] = 0;
        __syncthreads();
        int ev = e0 + ((e1 - e0) & ~3);   // e0 % 4 == 0, so int4 loads aligned
        for (int e = e0 + t * 4; e < ev; e += 1024) {
            int4 d4 = *(const int4*)(dstv + e);
            *(int4*)&dcache[e - e0] = d4;
            atomicAdd(&h[d4.x >> BUCK_LOG], 1);
            atomicAdd(&h[d4.y >> BUCK_LOG], 1);
            atomicAdd(&h[d4.z >> BUCK_LOG], 1);
            atomicAdd(&h[d4.w >> BUCK_LOG], 1);
        }
        for (int e = ev + t; e < e1; e += 256) {
            int d = dstv[e];
            dcache[e - e0] = d;
            atomicAdd(&h[d >> BUCK_LOG], 1);
        }
        __syncthreads();
        for (int i = t; i < NBUCK; i += 256) {
            int c = h[i];
            lcur[i] = c ? atomicAdd(&bcur0[i], c) : 0;
        }
        __syncthreads();
        for (int e = e0 + t * 4; e < ev; e += 1024) {
            int4 d4 = *(const int4*)&dcache[e - e0];
            int4 s4 = *(const int4*)(srcv + e);
            int b0 = d4.x >> BUCK_LOG, b1 = d4.y >> BUCK_LOG;
            int b2 = d4.z >> BUCK_LOG, b3 = d4.w >> BUCK_LOG;
            int p0 = atomicAdd(&lcur[b0], 1);
            int p1 = atomicAdd(&lcur[b1], 1);
            int p2 = atomicAdd(&lcur[b2], 1);
            int p3 = atomicAdd(&lcur[b3], 1);
            if (p0 < BCAP) packed[b0 * BCAP + p0] = ((d4.x & (BUCK_W - 1)) << 20) | s4.x;
            if (p1 < BCAP) packed[b1 * BCAP + p1] = ((d4.y & (BUCK_W - 1)) << 20) | s4.y;
            if (p2 < BCAP) packed[b2 * BCAP + p2] = ((d4.z & (BUCK_W - 1)) << 20) | s4.z;
            if (p3 < BCAP) packed[b3 * BCAP + p3] = ((d4.w & (BUCK_W - 1)) << 20) | s4.w;
        }
        for (int e = ev + t; e < e1; e += 256) {
            int d = dcache[e - e0];
            int bk = d >> BUCK_LOG;
            int pos = atomicAdd(&lcur[bk], 1);
            if (pos < BCAP) packed[bk * BCAP + pos] = ((d & (BUCK_W - 1)) << 20) | srcv[e];
        }
    } else if (b < FILL_BLOCKS + CVT_BLOCKS) {
        size_t i = ((size_t)(b - FILL_BLOCKS) * 256 + t) * 8;
        float4 v0 = *(const float4*)(x + i);
        float4 v1 = *(const float4*)(x + i + 4);
        half8 o;
        o[0] = (_Float16)v0.x; o[1] = (_Float16)v0.y; o[2] = (_Float16)v0.z; o[3] = (_Float16)v0.w;
        o[4] = (_Float16)v1.x; o[5] = (_Float16)v1.y; o[6] = (_Float16)v1.z; o[7] = (_Float16)v1.w;
        *(half8*)(X16 + i) = o;
    } else if (b < FILL_BLOCKS + CVT_BLOCKS + GST_BLOCKS) {
        int n = (b - FILL_BLOCKS - CVT_BLOCKS) * 256 + t;
        if (n < N_NODES) {
            int bb = batch[n];
            int prev = (n == 0) ? -1 : batch[n - 1];
            for (int g = prev + 1; g <= bb; ++g) gstart[g] = n;
            if (n == N_NODES - 1)
                for (int g = bb + 1; g <= N_GRAPHS; ++g) gstart[g] = N_NODES;
        }
    } else {
        // P[mat][((ct*4+ks)*64+lane)*8+j] = f16(W[k][col]); col=ct*16+(lane&15), k=ks*32+(lane>>4)*8+j
        int gid = (b - FILL_BLOCKS - CVT_BLOCKS - GST_BLOCKS) * 256 + t;   // 0..8191
        int mat = gid >> 11;
        int r = gid & 2047;
        int ctks = r >> 6;
        int lane = r & 63;
        int col = (ctks >> 2) * 16 + (lane & 15);
        int k0 = (ctks & 3) * 32 + (lane >> 4) * 8;
        const float* W = (mat == 0) ? W1a : (mat == 1) ? W1b : (mat == 2) ? W2a : W2b;
        _Float16* dp = P + mat * 16384 + r * 8;
#pragma unroll
        for (int j = 0; j < 8; ++j) dp[j] = (_Float16)W[(k0 + j) * HID + col];
    }
}

// ---- CSR finalize: per-bucket block computes its own global prefix, then local sort ----
__global__ __launch_bounds__(256) void k_csrfine(const int* __restrict__ packed,
                                                 const int* __restrict__ bcur0,
                                                 int* __restrict__ offsets,
                                                 int* __restrict__ csr_src) {
    __shared__ int hist[BUCK_W];
    __shared__ int scan[BUCK_W];
    __shared__ int cur[BUCK_W];
    __shared__ int red[4];
    int b = blockIdx.x;
    int base = b << BUCK_LOG;
    int t = threadIdx.x;
    // boff[b] = sum_{i<b} bcur0[i]  (<=781 L2-hot ints, block reduce)
    int partial = 0;
    for (int j = t; j < b; j += 256) partial += bcur0[j];
#pragma unroll
    for (int d = 32; d > 0; d >>= 1) partial += __shfl_down(partial, d, 64);
    if ((t & 63) == 0) red[t >> 6] = partial;
    __syncthreads();
    int s = red[0] + red[1] + red[2] + red[3];
    int cnt = bcur0[b];
    if (cnt > BCAP) cnt = BCAP;
    const int* pb = packed + b * BCAP;

    if (t < BUCK_W) hist[t] = 0;
    __syncthreads();
    for (int i = t; i < cnt; i += 256) atomicAdd(&hist[pb[i] >> 20], 1);
    __syncthreads();
    if (t < BUCK_W) scan[t] = hist[t];
    __syncthreads();
    for (int d = 1; d < BUCK_W; d <<= 1) {
        int a = 0;
        if (t >= d && t < BUCK_W) a = scan[t - d];
        __syncthreads();
        if (t < BUCK_W) scan[t] += a;
        __syncthreads();
    }
    if (t < BUCK_W) {
        int node = base + t;
        if (node < N_NODES) {
            int excl = scan[t] - hist[t];
            offsets[node] = s + excl;
            cur[t] = excl;
        }
    }
    if (b == 0 && t == 0) offsets[N_NODES] = N_EDGES;
    __syncthreads();
    for (int i = t; i < cnt; i += 256) {
        int v = pb[i];
        int ln = v >> 20;
        int pos = atomicAdd(&cur[ln], 1);
        csr_src[s + pos] = v & 0xFFFFF;
    }
}

// ---- gather-sum (fp16): 1 node/wave, 16B/lane rows, wave-batched index load ----
// (Measured 57.7us, FETCH pinned at ~188MB across 3 structures: fabric floor.)
static __device__ __forceinline__ half8 shfl_xor_h8(half8 v, int mask) {
    union { half8 h; int i[4]; } a, b;
    a.h = v;
#pragma unroll
    for (int k = 0; k < 4; ++k) b.i[k] = __shfl_xor(a.i[k], mask, 64);
    return b.h;
}

__global__ __launch_bounds__(256) void k_gather16(const _Float16* __restrict__ x,
                                                  const int* __restrict__ csr,
                                                  const int* __restrict__ offs,
                                                  _Float16* __restrict__ out) {
    int t = threadIdx.x;
    int wave = t >> 6, lane = t & 63;
    int g = lane >> 4;        // edge slot 0..3 within a 4-edge step
    int l = lane & 15;        // 16B slice within row
    int node = __builtin_amdgcn_readfirstlane(blockIdx.x * 4 + wave);
    const half8* xp8 = (const half8*)x;
    int s = offs[node], e = offs[node + 1];

    half8 z = {0, 0, 0, 0, 0, 0, 0, 0};
    half8 acc0 = (g == 0) ? xp8[(size_t)node * 16 + l] : z;   // own row once
    half8 acc1 = z;

    for (int base = s; base < e; base += 64) {
        int cnt = e - base;
        if (cnt > 64) cnt = 64;
        int myidx = (base + lane < e) ? csr[base + lane] : 0;
        int j = 0;
        for (; j + 16 <= cnt; j += 16) {
            int i0 = __shfl(myidx, j + g, 64);
            int i1 = __shfl(myidx, j + 4 + g, 64);
            int i2 = __shfl(myidx, j + 8 + g, 64);
            int i3 = __shfl(myidx, j + 12 + g, 64);
            acc0 += xp8[(size_t)i0 * 16 + l];
            acc1 += xp8[(size_t)i1 * 16 + l];
            acc0 += xp8[(size_t)i2 * 16 + l];
            acc1 += xp8[(size_t)i3 * 16 + l];
        }
        for (; j < cnt; j += 4) {
            int sl = j + g;
            int idx = __shfl(myidx, sl < cnt ? sl : 0, 64);
            if (sl < cnt) acc0 += xp8[(size_t)idx * 16 + l];
        }
    }
    // combine the 4 groups' partials (lanes l, l+16, l+32, l+48 hold slice l)
    half8 r = acc0 + acc1;
    r += shfl_xor_h8(r, 16);
    r += shfl_xor_h8(r, 32);
    if (g == 0) ((half8*)out)[(size_t)node * 16 + l] = r;
}

// ---------------- fused MLP (f16 MFMA, transposed operands, row-major IO) ----------------
static __device__ __forceinline__ unsigned long long pack4(float v0, float v1,
                                                           float v2, float v3) {
    union { h2 h[2]; unsigned long long u; } u;
    h2 p0, p1;
    p0[0] = (_Float16)v0; p0[1] = (_Float16)v1;
    p1[0] = (_Float16)v2; p1[1] = (_Float16)v3;
    u.h[0] = p0; u.h[1] = p1;
    return u.u;
}

template <int RELU_OUT>
__global__ __launch_bounds__(256, 2) void k_mlp16(const _Float16* __restrict__ in,
                                                  const _Float16* __restrict__ Wap,
                                                  const float* __restrict__ ba,
                                                  const _Float16* __restrict__ Wbp,
                                                  const float* __restrict__ bb,
                                                  _Float16* __restrict__ out) {
    __shared__ uint4 WaS4[2048];               // 32 KB
    __shared__ uint4 WbS4[2048];               // 32 KB
    __shared__ unsigned long long hS[4][512];  // 16 KB
    int t = threadIdx.x;
    int wave = t >> 6, lane = t & 63;
    int l = lane & 15, w = lane >> 4;
    int row0 = blockIdx.x * 256 + wave * 64;

    const uint4* wa4 = (const uint4*)Wap;
    const uint4* wb4 = (const uint4*)Wbp;
#pragma unroll
    for (int i = 0; i < 8; ++i) WaS4[t + i * 256] = wa4[t + i * 256];
#pragma unroll
    for (int i = 0; i < 8; ++i) WbS4[t + i * 256] = wb4[t + i * 256];
    __syncthreads();
    const half8* waf = (const half8*)WaS4;
    const half8* wbf = (const half8*)WbS4;
    unsigned long long* h64 = hS[wave];
    int swz = ((l & 3) << 2) ^ (((l >> 2) & 1) << 1);

    float4 baR[8], bbR[8];
#pragma unroll
    for (int ct = 0; ct < 8; ++ct) {
        baR[ct] = *(const float4*)(ba + ct * 16 + w * 4);
        bbR[ct] = *(const float4*)(bb + ct * 16 + w * 4);
    }

#pragma unroll
    for (int tile = 0; tile < 4; ++tile) {
        int row = row0 + tile * 16 + l;
        bool rok = row < N_NODES;
        const _Float16* rp = in + (size_t)row * HID + w * 8;
        half8 xf[4];
#pragma unroll
        for (int ks = 0; ks < 4; ++ks) {
            half8 v = {0, 0, 0, 0, 0, 0, 0, 0};
            if (rok) v = *(const half8*)(rp + ks * 32);
            xf[ks] = v;
        }
        // GEMM1: h^T = Wa^T @ x^T ; lane holds row l, regs = 4 consecutive h-cols
#pragma unroll
        for (int ct = 0; ct < 8; ++ct) {
            f32x4 c = {0.f, 0.f, 0.f, 0.f};
#pragma unroll
            for (int ks = 0; ks < 4; ++ks)
                c = __builtin_amdgcn_mfma_f32_16x16x32_f16(waf[(ct * 4 + ks) * 64 + lane],
                                                           xf[ks], c, 0, 0, 0);
            float4 b4 = baR[ct];
            h64[l * 32 + ((ct * 4 + w) ^ swz)] =
                pack4(fmaxf(c[0] + b4.x, 0.f), fmaxf(c[1] + b4.y, 0.f),
                      fmaxf(c[2] + b4.z, 0.f), fmaxf(c[3] + b4.w, 0.f));
        }
        half8 hf[4];
#pragma unroll
        for (int ks = 0; ks < 4; ++ks) {
            int slot = (ks * 8 + w * 2) ^ swz;
            hf[ks] = *(const half8*)&h64[l * 32 + slot];
        }
        // GEMM2: out^T = Wb^T @ h^T ; direct 8B stores
#pragma unroll
        for (int ct = 0; ct < 8; ++ct) {
            f32x4 c = {0.f, 0.f, 0.f, 0.f};
#pragma unroll
            for (int ks = 0; ks < 4; ++ks)
                c = __builtin_amdgcn_mfma_f32_16x16x32_f16(wbf[(ct * 4 + ks) * 64 + lane],
                                                           hf[ks], c, 0, 0, 0);
            float4 b4 = bbR[ct];
            float v0 = c[0] + b4.x, v1 = c[1] + b4.y, v2 = c[2] + b4.z, v3 = c[3] + b4.w;
            if (RELU_OUT) {
                v0 = fmaxf(v0, 0.f); v1 = fmaxf(v1, 0.f);
                v2 = fmaxf(v2, 0.f); v3 = fmaxf(v3, 0.f);
            }
            if (rok)
                *(unsigned long long*)(out + (size_t)row * HID + ct * 16 + w * 4) =
                    pack4(v0, v1, v2, v3);
        }
    }
}

// ---------------- fused MLP2 + mean-pool: no H2 array, atomic per-graph sums ----------------
// After GEMM2, lanes w*16+l (fixed w) hold rows l=0..15 of a tile at cols
// ct*16+w*4..+3. Nodes are graph-sorted -> tile is usually graph-uniform:
// 4-round shfl_xor over l gives the per-col row-sum, one lane atomicAdds it.
// Boundary tiles (~1000) take the per-lane atomic slow path. Pooling sums
// UNROUNDED f32 MFMA outputs (better than fp16 H2 round-trip).
__global__ __launch_bounds__(256, 2) void k_mlp2pool(const _Float16* __restrict__ in,
                                                     const _Float16* __restrict__ Wap,
                                                     const float* __restrict__ ba,
                                                     const _Float16* __restrict__ Wbp,
                                                     const float* __restrict__ bb,
                                                     const int* __restrict__ batch,
                                                     float* __restrict__ pooled) {
    __shared__ uint4 WaS4[2048];               // 32 KB
    __shared__ uint4 WbS4[2048];               // 32 KB
    __shared__ unsigned long long hS[4][512];  // 16 KB
    int t = threadIdx.x;
    int wave = t >> 6, lane = t & 63;
    int l = lane & 15, w = lane >> 4;
    int row0 = blockIdx.x * 256 + wave * 64;

    const uint4* wa4 = (const uint4*)Wap;
    const uint4* wb4 = (const uint4*)Wbp;
#pragma unroll
    for (int i = 0; i < 8; ++i) WaS4[t + i * 256] = wa4[t + i * 256];
#pragma unroll
    for (int i = 0; i < 8; ++i) WbS4[t + i * 256] = wb4[t + i * 256];
    __syncthreads();
    const half8* waf = (const half8*)WaS4;
    const half8* wbf = (const half8*)WbS4;
    unsigned long long* h64 = hS[wave];
    int swz = ((l & 3) << 2) ^ (((l >> 2) & 1) << 1);

    float4 baR[8], bbR[8];
#pragma unroll
    for (int ct = 0; ct < 8; ++ct) {
        baR[ct] = *(const float4*)(ba + ct * 16 + w * 4);
        bbR[ct] = *(const float4*)(bb + ct * 16 + w * 4);
    }

#pragma unroll
    for (int tile = 0; tile < 4; ++tile) {
        int row = row0 + tile * 16 + l;
        bool rok = row < N_NODES;
        int rowc = rok ? row : (N_NODES - 1);
        int g = batch[rowc];
        // graph-uniformity of this 16-row tile (shfl_xor m<16 stays in w-group;
        // rows depend only on l, so all 4 w-groups agree)
        int mn = g, mx = g;
#pragma unroll
        for (int m = 1; m < 16; m <<= 1) {
            mn = min(mn, __shfl_xor(mn, m, 64));
            mx = max(mx, __shfl_xor(mx, m, 64));
        }
        bool uni = (mn == mx);

        const _Float16* rp = in + (size_t)row * HID + w * 8;
        half8 xf[4];
#pragma unroll
        for (int ks = 0; ks < 4; ++ks) {
            half8 v = {0, 0, 0, 0, 0, 0, 0, 0};
            if (rok) v = *(const half8*)(rp + ks * 32);
            xf[ks] = v;
        }
        // GEMM1 + ReLU -> hS
#pragma unroll
        for (int ct = 0; ct < 8; ++ct) {
            f32x4 c = {0.f, 0.f, 0.f, 0.f};
#pragma unroll
            for (int ks = 0; ks < 4; ++ks)
                c = __builtin_amdgcn_mfma_f32_16x16x32_f16(waf[(ct * 4 + ks) * 64 + lane],
                                                           xf[ks], c, 0, 0, 0);
            float4 b4 = baR[ct];
            h64[l * 32 + ((ct * 4 + w) ^ swz)] =
                pack4(fmaxf(c[0] + b4.x, 0.f), fmaxf(c[1] + b4.y, 0.f),
                      fmaxf(c[2] + b4.z, 0.f), fmaxf(c[3] + b4.w, 0.f));
        }
        half8 hf[4];
#pragma unroll
        for (int ks = 0; ks < 4; ++ks) {
            int slot = (ks * 8 + w * 2) ^ swz;
            hf[ks] = *(const half8*)&h64[l * 32 + slot];
        }
        // GEMM2 (no relu) -> per-graph pooled sums
#pragma unroll
        for (int ct = 0; ct < 8; ++ct) {
            f32x4 c = {0.f, 0.f, 0.f, 0.f};
#pragma unroll
            for (int ks = 0; ks < 4; ++ks)
                c = __builtin_amdgcn_mfma_f32_16x16x32_f16(wbf[(ct * 4 + ks) * 64 + lane],
                                                           hf[ks], c, 0, 0, 0);
            float4 b4 = bbR[ct];
            float v0 = c[0] + b4.x, v1 = c[1] + b4.y, v2 = c[2] + b4.z, v3 = c[3] + b4.w;
            if (!rok) { v0 = 0.f; v1 = 0.f; v2 = 0.f; v3 = 0.f; }   // no bias for pad rows
            if (uni) {
#pragma unroll
                for (int m = 1; m < 16; m <<= 1) {
                    v0 += __shfl_xor(v0, m, 64);
                    v1 += __shfl_xor(v1, m, 64);
                    v2 += __shfl_xor(v2, m, 64);
                    v3 += __shfl_xor(v3, m, 64);
                }
                if (l == 0) {
                    float* pp = pooled + (size_t)g * HID + ct * 16 + w * 4;
                    atomicAdd(pp + 0, v0);
                    atomicAdd(pp + 1, v1);
                    atomicAdd(pp + 2, v2);
                    atomicAdd(pp + 3, v3);
                }
            } else if (rok) {
                float* pp = pooled + (size_t)g * HID + ct * 16 + w * 4;
                atomicAdd(pp + 0, v0);
                atomicAdd(pp + 1, v1);
                atomicAdd(pp + 2, v2);
                atomicAdd(pp + 3, v3);
            }
        }
    }
}

// ---------------- head: out = (pooled/cnt) @ Wlin + blin ----------------
__global__ __launch_bounds__(64) void k_head(const float* __restrict__ pooled,
                                             const int* __restrict__ gstart,
                                             const float* __restrict__ Wlin,
                                             const float* __restrict__ blin,
                                             float* __restrict__ out) {
    int g = blockIdx.x;
    int lane = threadIdx.x;
    int s = gstart[g], e = gstart[g + 1];
    float c = fmaxf((float)(e - s), 1.0f);
    float px = pooled[(size_t)g * HID + 2 * lane] / c;
    float py = pooled[(size_t)g * HID + 2 * lane + 1] / c;
#pragma unroll
    for (int o = 0; o < OUTD; ++o) {
        float v = px * Wlin[(2 * lane) * OUTD + o] + py * Wlin[(2 * lane + 1) * OUTD + o];
#pragma unroll
        for (int d = 32; d > 0; d >>= 1) v += __shfl_down(v, d, 64);
        if (lane == 0) out[g * OUTD + o] = v + blin[o];
    }
}

extern "C" void kernel_launch(void* const* d_in, const int* in_sizes, int n_in,
                              void* d_out, int out_size, void* d_ws, size_t ws_size,
                              hipStream_t stream) {
    const float* x    = (const float*)d_in[0];
    const int*   ei   = (const int*)d_in[1];
    const int*   batch= (const int*)d_in[2];
    const float* W1a  = (const float*)d_in[3];
    const float* b1a  = (const float*)d_in[4];
    const float* W1b  = (const float*)d_in[5];
    const float* b1b  = (const float*)d_in[6];
    const float* W2a  = (const float*)d_in[7];
    const float* b2a  = (const float*)d_in[8];
    const float* W2b  = (const float*)d_in[9];
    const float* b2b  = (const float*)d_in[10];
    const float* Wlin = (const float*)d_in[11];
    const float* blin = (const float*)d_in[12];
    const int* src = ei;
    const int* dst = ei + N_EDGES;
    float* out = (float*)d_out;

    char* ws = (char*)d_ws;
    size_t off = 0;
    auto alloc = [&](size_t bytes) -> void* {
        void* p = ws + off;
        off += (bytes + 255) & ~(size_t)255;
        return p;
    };
    _Float16* X16 = (_Float16*)alloc(2ull * N_NODES * HID);          // 25.6 MB
    _Float16* M   = (_Float16*)alloc(2ull * N_NODES * HID + 65536);  // 25.6 MB
    _Float16* H1  = (_Float16*)alloc(2ull * N_NODES * HID + 65536);  // 25.6 MB
    int*   csr_src = (int*)alloc(sizeof(int) * (size_t)N_EDGES);     // 6.4 MB
    int*   offsets = (int*)alloc(sizeof(int) * (N_NODES + 1));
    int*   gstart  = (int*)alloc(sizeof(int) * (N_GRAPHS + 1));
    // bcur0 + pooled contiguous: one memset clears both
    int*   bcur0   = (int*)alloc(sizeof(int) * NBUCK + sizeof(float) * N_GRAPHS * HID);
    float* pooled  = (float*)(bcur0 + NBUCK);
    _Float16* Wpack = (_Float16*)alloc(2ull * 4 * 16384);            // 128 KB
    int* packed = (int*)H1;             // 8 MB padded buckets; alias: consumed before mlp1 writes H1
    _Float16* M2 = M;                   // alias: M dead after mlp1
    (void)ws_size; (void)in_sizes; (void)n_in; (void)out_size;

    hipMemsetAsync(bcur0, 0, sizeof(int) * NBUCK + sizeof(float) * N_GRAPHS * HID, stream);

    // fused prep (padded-bucket fill FIRST for overlap, then cvt + gstart + pack_w)
    k_prep<<<PREP_BLOCKS, 256, 0, stream>>>(x, batch, src, dst, W1a, W1b, W2a, W2b,
                                            X16, gstart, Wpack, bcur0, packed);
    // CSR finalize (self-computed bucket prefix)
    k_csrfine<<<NBUCK, 256, 0, stream>>>(packed, bcur0, offsets, csr_src);

    // layer 1
    k_gather16<<<N_NODES / 4, 256, 0, stream>>>(X16, csr_src, offsets, M);
    k_mlp16<1><<<(N_NODES + 255) / 256, 256, 0, stream>>>(M, Wpack + 0 * 16384, b1a,
                                                          Wpack + 1 * 16384, b1b, H1);
    // layer 2 (mlp2 fused with mean-pool: no H2 array)
    k_gather16<<<N_NODES / 4, 256, 0, stream>>>(H1, csr_src, offsets, M2);
    k_mlp2pool<<<(N_NODES + 255) / 256, 256, 0, stream>>>(M2, Wpack + 2 * 16384, b2a,
                                                          Wpack + 3 * 16384, b2b, batch, pooled);

    // head
    k_head<<<N_GRAPHS, 64, 0, stream>>>(pooled, gstart, Wlin, blin, out);
}

// Round 10
// 305.001 us; speedup vs baseline: 1.4656x; 1.4656x over previous
//
#include <hip/hip_runtime.h>

#define N_NODES 100000
#define N_EDGES 1600000
#define N_GRAPHS 1000
#define HID 128
#define OUTD 6

#define BUCK_LOG 7
#define BUCK_W (1 << BUCK_LOG)                      // 128 nodes per bucket
#define NBUCK ((N_NODES + BUCK_W - 1) >> BUCK_LOG)  // 782
#define BCAP 2560                                    // mean 2048, sigma~45 -> +11 sigma
#define FILL_BLOCKS 512
#define FILL_CHUNK 3128   // multiple of 4; 512*3128 = 1601536 >= N_EDGES

#define CVT_BLOCKS 6250   // 12.8M elems / (8*256)
#define GST_BLOCKS 391
#define PACK_BLOCKS 32
#define PREP_BLOCKS (CVT_BLOCKS + GST_BLOCKS + PACK_BLOCKS + FILL_BLOCKS)

typedef _Float16 h2 __attribute__((ext_vector_type(2)));
typedef _Float16 half8 __attribute__((ext_vector_type(8)));
typedef float f32x4 __attribute__((ext_vector_type(4)));

// ---- fused prep: bucket-fill FIRST (overlaps cvt), x->fp16, gstart, weight pack ----
// Fill: hist pass caches dst chunk in LDS -> scatter pass re-reads dst from LDS
// (one global pass over dstv instead of two).
__global__ __launch_bounds__(256) void k_prep(const float* __restrict__ x,
                                              const int* __restrict__ batch,
                                              const int* __restrict__ srcv,
                                              const int* __restrict__ dstv,
                                              const float* __restrict__ W1a,
                                              const float* __restrict__ W1b,
                                              const float* __restrict__ W2a,
                                              const float* __restrict__ W2b,
                                              _Float16* __restrict__ X16,
                                              int* __restrict__ gstart,
                                              _Float16* __restrict__ P,
                                              int* __restrict__ bcur0,
                                              int* __restrict__ packed) {
    __shared__ int h[NBUCK];
    __shared__ int lcur[NBUCK];
    __shared__ int dcache[FILL_CHUNK];   // 12.5 KB dst chunk cache
    int b = blockIdx.x, t = threadIdx.x;
    if (b < FILL_BLOCKS) {
        // ---- bucket fill (scheduled first: latency-bound, overlaps BW-bound cvt) ----
        // Scatter targets are bucket-contiguous regions -> lines coalesce in L2.
        int e0 = b * FILL_CHUNK;
        int e1 = min(e0 + FILL_CHUNK, N_EDGES);
        for (int i = t; i < NBUCK; i += 256) h[i] = 0;
        __syncthreads();
        int ev = e0 + ((e1 - e0) & ~3);   // e0 % 4 == 0, so int4 loads aligned
        for (int e = e0 + t * 4; e < ev; e += 1024) {
            int4 d4 = *(const int4*)(dstv + e);
            *(int4*)&dcache[e - e0] = d4;
            atomicAdd(&h[d4.x >> BUCK_LOG], 1);
            atomicAdd(&h[d4.y >> BUCK_LOG], 1);
            atomicAdd(&h[d4.z >> BUCK_LOG], 1);
            atomicAdd(&h[d4.w >> BUCK_LOG], 1);
        }
        for (int e = ev + t; e < e1; e += 256) {
            int d = dstv[e];
            dcache[e - e0] = d;
            atomicAdd(&h[d >> BUCK_LOG], 1);
        }
        __syncthreads();
        for (int i = t; i < NBUCK; i += 256) {
            int c = h[i];
            lcur[i] = c ? atomicAdd(&bcur0[i], c) : 0;
        }
        __syncthreads();
        for (int e = e0 + t * 4; e < ev; e += 1024) {
            int4 d4 = *(const int4*)&dcache[e - e0];
            int4 s4 = *(const int4*)(srcv + e);
            int b0 = d4.x >> BUCK_LOG, b1 = d4.y >> BUCK_LOG;
            int b2 = d4.z >> BUCK_LOG, b3 = d4.w >> BUCK_LOG;
            int p0 = atomicAdd(&lcur[b0], 1);
            int p1 = atomicAdd(&lcur[b1], 1);
            int p2 = atomicAdd(&lcur[b2], 1);
            int p3 = atomicAdd(&lcur[b3], 1);
            if (p0 < BCAP) packed[b0 * BCAP + p0] = ((d4.x & (BUCK_W - 1)) << 20) | s4.x;
            if (p1 < BCAP) packed[b1 * BCAP + p1] = ((d4.y & (BUCK_W - 1)) << 20) | s4.y;
            if (p2 < BCAP) packed[b2 * BCAP + p2] = ((d4.z & (BUCK_W - 1)) << 20) | s4.z;
            if (p3 < BCAP) packed[b3 * BCAP + p3] = ((d4.w & (BUCK_W - 1)) << 20) | s4.w;
        }
        for (int e = ev + t; e < e1; e += 256) {
            int d = dcache[e - e0];
            int bk = d >> BUCK_LOG;
            int pos = atomicAdd(&lcur[bk], 1);
            if (pos < BCAP) packed[bk * BCAP + pos] = ((d & (BUCK_W - 1)) << 20) | srcv[e];
        }
    } else if (b < FILL_BLOCKS + CVT_BLOCKS) {
        size_t i = ((size_t)(b - FILL_BLOCKS) * 256 + t) * 8;
        float4 v0 = *(const float4*)(x + i);
        float4 v1 = *(const float4*)(x + i + 4);
        half8 o;
        o[0] = (_Float16)v0.x; o[1] = (_Float16)v0.y; o[2] = (_Float16)v0.z; o[3] = (_Float16)v0.w;
        o[4] = (_Float16)v1.x; o[5] = (_Float16)v1.y; o[6] = (_Float16)v1.z; o[7] = (_Float16)v1.w;
        *(half8*)(X16 + i) = o;
    } else if (b < FILL_BLOCKS + CVT_BLOCKS + GST_BLOCKS) {
        int n = (b - FILL_BLOCKS - CVT_BLOCKS) * 256 + t;
        if (n < N_NODES) {
            int bb = batch[n];
            int prev = (n == 0) ? -1 : batch[n - 1];
            for (int g = prev + 1; g <= bb; ++g) gstart[g] = n;
            if (n == N_NODES - 1)
                for (int g = bb + 1; g <= N_GRAPHS; ++g) gstart[g] = N_NODES;
        }
    } else {
        // P[mat][((ct*4+ks)*64+lane)*8+j] = f16(W[k][col]); col=ct*16+(lane&15), k=ks*32+(lane>>4)*8+j
        int gid = (b - FILL_BLOCKS - CVT_BLOCKS - GST_BLOCKS) * 256 + t;   // 0..8191
        int mat = gid >> 11;
        int r = gid & 2047;
        int ctks = r >> 6;
        int lane = r & 63;
        int col = (ctks >> 2) * 16 + (lane & 15);
        int k0 = (ctks & 3) * 32 + (lane >> 4) * 8;
        const float* W = (mat == 0) ? W1a : (mat == 1) ? W1b : (mat == 2) ? W2a : W2b;
        _Float16* dp = P + mat * 16384 + r * 8;
#pragma unroll
        for (int j = 0; j < 8; ++j) dp[j] = (_Float16)W[(k0 + j) * HID + col];
    }
}

// ---- CSR finalize: per-bucket block computes its own global prefix, then local sort ----
__global__ __launch_bounds__(256) void k_csrfine(const int* __restrict__ packed,
                                                 const int* __restrict__ bcur0,
                                                 int* __restrict__ offsets,
                                                 int* __restrict__ csr_src) {
    __shared__ int hist[BUCK_W];
    __shared__ int scan[BUCK_W];
    __shared__ int cur[BUCK_W];
    __shared__ int red[4];
    int b = blockIdx.x;
    int base = b << BUCK_LOG;
    int t = threadIdx.x;
    // boff[b] = sum_{i<b} bcur0[i]  (<=781 L2-hot ints, block reduce)
    int partial = 0;
    for (int j = t; j < b; j += 256) partial += bcur0[j];
#pragma unroll
    for (int d = 32; d > 0; d >>= 1) partial += __shfl_down(partial, d, 64);
    if ((t & 63) == 0) red[t >> 6] = partial;
    __syncthreads();
    int s = red[0] + red[1] + red[2] + red[3];
    int cnt = bcur0[b];
    if (cnt > BCAP) cnt = BCAP;
    const int* pb = packed + b * BCAP;

    if (t < BUCK_W) hist[t] = 0;
    __syncthreads();
    for (int i = t; i < cnt; i += 256) atomicAdd(&hist[pb[i] >> 20], 1);
    __syncthreads();
    if (t < BUCK_W) scan[t] = hist[t];
    __syncthreads();
    for (int d = 1; d < BUCK_W; d <<= 1) {
        int a = 0;
        if (t >= d && t < BUCK_W) a = scan[t - d];
        __syncthreads();
        if (t < BUCK_W) scan[t] += a;
        __syncthreads();
    }
    if (t < BUCK_W) {
        int node = base + t;
        if (node < N_NODES) {
            int excl = scan[t] - hist[t];
            offsets[node] = s + excl;
            cur[t] = excl;
        }
    }
    if (b == 0 && t == 0) offsets[N_NODES] = N_EDGES;
    __syncthreads();
    for (int i = t; i < cnt; i += 256) {
        int v = pb[i];
        int ln = v >> 20;
        int pos = atomicAdd(&cur[ln], 1);
        csr_src[s + pos] = v & 0xFFFFF;
    }
}

// ---- gather-sum (fp16): 1 node/wave, 16B/lane rows, wave-batched index load ----
// (Measured 57.5us, FETCH pinned at ~188MB across 3 structures: fabric floor.)
static __device__ __forceinline__ half8 shfl_xor_h8(half8 v, int mask) {
    union { half8 h; int i[4]; } a, b;
    a.h = v;
#pragma unroll
    for (int k = 0; k < 4; ++k) b.i[k] = __shfl_xor(a.i[k], mask, 64);
    return b.h;
}

__global__ __launch_bounds__(256) void k_gather16(const _Float16* __restrict__ x,
                                                  const int* __restrict__ csr,
                                                  const int* __restrict__ offs,
                                                  _Float16* __restrict__ out) {
    int t = threadIdx.x;
    int wave = t >> 6, lane = t & 63;
    int g = lane >> 4;        // edge slot 0..3 within a 4-edge step
    int l = lane & 15;        // 16B slice within row
    int node = __builtin_amdgcn_readfirstlane(blockIdx.x * 4 + wave);
    const half8* xp8 = (const half8*)x;
    int s = offs[node], e = offs[node + 1];

    half8 z = {0, 0, 0, 0, 0, 0, 0, 0};
    half8 acc0 = (g == 0) ? xp8[(size_t)node * 16 + l] : z;   // own row once
    half8 acc1 = z;

    for (int base = s; base < e; base += 64) {
        int cnt = e - base;
        if (cnt > 64) cnt = 64;
        int myidx = (base + lane < e) ? csr[base + lane] : 0;
        int j = 0;
        for (; j + 16 <= cnt; j += 16) {
            int i0 = __shfl(myidx, j + g, 64);
            int i1 = __shfl(myidx, j + 4 + g, 64);
            int i2 = __shfl(myidx, j + 8 + g, 64);
            int i3 = __shfl(myidx, j + 12 + g, 64);
            acc0 += xp8[(size_t)i0 * 16 + l];
            acc1 += xp8[(size_t)i1 * 16 + l];
            acc0 += xp8[(size_t)i2 * 16 + l];
            acc1 += xp8[(size_t)i3 * 16 + l];
        }
        for (; j < cnt; j += 4) {
            int sl = j + g;
            int idx = __shfl(myidx, sl < cnt ? sl : 0, 64);
            if (sl < cnt) acc0 += xp8[(size_t)idx * 16 + l];
        }
    }
    // combine the 4 groups' partials (lanes l, l+16, l+32, l+48 hold slice l)
    half8 r = acc0 + acc1;
    r += shfl_xor_h8(r, 16);
    r += shfl_xor_h8(r, 32);
    if (g == 0) ((half8*)out)[(size_t)node * 16 + l] = r;
}

// ---------------- fused MLP (f16 MFMA, transposed operands, row-major IO) ----------------
static __device__ __forceinline__ unsigned long long pack4(float v0, float v1,
                                                           float v2, float v3) {
    union { h2 h[2]; unsigned long long u; } u;
    h2 p0, p1;
    p0[0] = (_Float16)v0; p0[1] = (_Float16)v1;
    p1[0] = (_Float16)v2; p1[1] = (_Float16)v3;
    u.h[0] = p0; u.h[1] = p1;
    return u.u;
}

template <int RELU_OUT>
__global__ __launch_bounds__(256, 2) void k_mlp16(const _Float16* __restrict__ in,
                                                  const _Float16* __restrict__ Wap,
                                                  const float* __restrict__ ba,
                                                  const _Float16* __restrict__ Wbp,
                                                  const float* __restrict__ bb,
                                                  _Float16* __restrict__ out) {
    __shared__ uint4 WaS4[2048];               // 32 KB
    __shared__ uint4 WbS4[2048];               // 32 KB
    __shared__ unsigned long long hS[4][512];  // 16 KB
    int t = threadIdx.x;
    int wave = t >> 6, lane = t & 63;
    int l = lane & 15, w = lane >> 4;
    int row0 = blockIdx.x * 256 + wave * 64;

    const uint4* wa4 = (const uint4*)Wap;
    const uint4* wb4 = (const uint4*)Wbp;
#pragma unroll
    for (int i = 0; i < 8; ++i) WaS4[t + i * 256] = wa4[t + i * 256];
#pragma unroll
    for (int i = 0; i < 8; ++i) WbS4[t + i * 256] = wb4[t + i * 256];
    __syncthreads();
    const half8* waf = (const half8*)WaS4;
    const half8* wbf = (const half8*)WbS4;
    unsigned long long* h64 = hS[wave];
    int swz = ((l & 3) << 2) ^ (((l >> 2) & 1) << 1);

    float4 baR[8], bbR[8];
#pragma unroll
    for (int ct = 0; ct < 8; ++ct) {
        baR[ct] = *(const float4*)(ba + ct * 16 + w * 4);
        bbR[ct] = *(const float4*)(bb + ct * 16 + w * 4);
    }

#pragma unroll
    for (int tile = 0; tile < 4; ++tile) {
        int row = row0 + tile * 16 + l;
        bool rok = row < N_NODES;
        const _Float16* rp = in + (size_t)row * HID + w * 8;
        half8 xf[4];
#pragma unroll
        for (int ks = 0; ks < 4; ++ks) {
            half8 v = {0, 0, 0, 0, 0, 0, 0, 0};
            if (rok) v = *(const half8*)(rp + ks * 32);
            xf[ks] = v;
        }
        // GEMM1: h^T = Wa^T @ x^T ; lane holds row l, regs = 4 consecutive h-cols
#pragma unroll
        for (int ct = 0; ct < 8; ++ct) {
            f32x4 c = {0.f, 0.f, 0.f, 0.f};
#pragma unroll
            for (int ks = 0; ks < 4; ++ks)
                c = __builtin_amdgcn_mfma_f32_16x16x32_f16(waf[(ct * 4 + ks) * 64 + lane],
                                                           xf[ks], c, 0, 0, 0);
            float4 b4 = baR[ct];
            h64[l * 32 + ((ct * 4 + w) ^ swz)] =
                pack4(fmaxf(c[0] + b4.x, 0.f), fmaxf(c[1] + b4.y, 0.f),
                      fmaxf(c[2] + b4.z, 0.f), fmaxf(c[3] + b4.w, 0.f));
        }
        half8 hf[4];
#pragma unroll
        for (int ks = 0; ks < 4; ++ks) {
            int slot = (ks * 8 + w * 2) ^ swz;
            hf[ks] = *(const half8*)&h64[l * 32 + slot];
        }
        // GEMM2: out^T = Wb^T @ h^T ; direct 8B stores
#pragma unroll
        for (int ct = 0; ct < 8; ++ct) {
            f32x4 c = {0.f, 0.f, 0.f, 0.f};
#pragma unroll
            for (int ks = 0; ks < 4; ++ks)
                c = __builtin_amdgcn_mfma_f32_16x16x32_f16(wbf[(ct * 4 + ks) * 64 + lane],
                                                           hf[ks], c, 0, 0, 0);
            float4 b4 = bbR[ct];
            float v0 = c[0] + b4.x, v1 = c[1] + b4.y, v2 = c[2] + b4.z, v3 = c[3] + b4.w;
            if (RELU_OUT) {
                v0 = fmaxf(v0, 0.f); v1 = fmaxf(v1, 0.f);
                v2 = fmaxf(v2, 0.f); v3 = fmaxf(v3, 0.f);
            }
            if (rok)
                *(unsigned long long*)(out + (size_t)row * HID + ct * 16 + w * 4) =
                    pack4(v0, v1, v2, v3);
        }
    }
}

// ---------------- fused mean-pool + head (row-major input) ----------------
__global__ __launch_bounds__(256) void k_pool_head(const _Float16* __restrict__ h,
                                                   const int* __restrict__ gstart,
                                                   const float* __restrict__ Wlin,
                                                   const float* __restrict__ blin,
                                                   float* __restrict__ out) {
    __shared__ float sums[4][HID];
    int g = blockIdx.x;
    int t = threadIdx.x;
    int wave = t >> 6, lane = t & 63;
    int s = gstart[g], e = gstart[g + 1];
    float ax = 0.f, ay = 0.f;
    const h2* hp = (const h2*)h;
    int r = s + wave;
    for (; r + 12 < e; r += 16) {
        h2 v0 = hp[(size_t)r * 64 + lane];
        h2 v1 = hp[(size_t)(r + 4) * 64 + lane];
        h2 v2 = hp[(size_t)(r + 8) * 64 + lane];
        h2 v3 = hp[(size_t)(r + 12) * 64 + lane];
        ax += (float)v0[0] + (float)v1[0] + (float)v2[0] + (float)v3[0];
        ay += (float)v0[1] + (float)v1[1] + (float)v2[1] + (float)v3[1];
    }
    for (; r < e; r += 4) {
        h2 v = hp[(size_t)r * 64 + lane];
        ax += (float)v[0];
        ay += (float)v[1];
    }
    sums[wave][2 * lane] = ax;
    sums[wave][2 * lane + 1] = ay;
    __syncthreads();
    if (wave != 0) return;
    float c = fmaxf((float)(e - s), 1.0f);
    float px = (sums[0][2 * lane] + sums[1][2 * lane] + sums[2][2 * lane] + sums[3][2 * lane]) / c;
    float py = (sums[0][2 * lane + 1] + sums[1][2 * lane + 1] + sums[2][2 * lane + 1] +
                sums[3][2 * lane + 1]) / c;
#pragma unroll
    for (int o = 0; o < OUTD; ++o) {
        float v = px * Wlin[(2 * lane) * OUTD + o] + py * Wlin[(2 * lane + 1) * OUTD + o];
#pragma unroll
        for (int d = 32; d > 0; d >>= 1) v += __shfl_down(v, d, 64);
        if (lane == 0) out[g * OUTD + o] = v + blin[o];
    }
}

extern "C" void kernel_launch(void* const* d_in, const int* in_sizes, int n_in,
                              void* d_out, int out_size, void* d_ws, size_t ws_size,
                              hipStream_t stream) {
    const float* x    = (const float*)d_in[0];
    const int*   ei   = (const int*)d_in[1];
    const int*   batch= (const int*)d_in[2];
    const float* W1a  = (const float*)d_in[3];
    const float* b1a  = (const float*)d_in[4];
    const float* W1b  = (const float*)d_in[5];
    const float* b1b  = (const float*)d_in[6];
    const float* W2a  = (const float*)d_in[7];
    const float* b2a  = (const float*)d_in[8];
    const float* W2b  = (const float*)d_in[9];
    const float* b2b  = (const float*)d_in[10];
    const float* Wlin = (const float*)d_in[11];
    const float* blin = (const float*)d_in[12];
    const int* src = ei;
    const int* dst = ei + N_EDGES;
    float* out = (float*)d_out;

    char* ws = (char*)d_ws;
    size_t off = 0;
    auto alloc = [&](size_t bytes) -> void* {
        void* p = ws + off;
        off += (bytes + 255) & ~(size_t)255;
        return p;
    };
    _Float16* X16 = (_Float16*)alloc(2ull * N_NODES * HID);          // 25.6 MB
    _Float16* M   = (_Float16*)alloc(2ull * N_NODES * HID + 65536);  // 25.6 MB
    _Float16* H1  = (_Float16*)alloc(2ull * N_NODES * HID + 65536);  // 25.6 MB
    int*   csr_src = (int*)alloc(sizeof(int) * (size_t)N_EDGES);     // 6.4 MB
    int*   offsets = (int*)alloc(sizeof(int) * (N_NODES + 1));
    int*   gstart  = (int*)alloc(sizeof(int) * (N_GRAPHS + 1));
    int*   bcur0   = (int*)alloc(sizeof(int) * NBUCK);
    _Float16* Wpack = (_Float16*)alloc(2ull * 4 * 16384);            // 128 KB
    int* packed = (int*)H1;             // 8 MB padded buckets; alias: consumed before mlp1 writes H1
    _Float16* M2 = M;                   // alias: M dead after mlp1
    _Float16* H2 = X16;                 // alias: X16 dead after gather1
    (void)ws_size; (void)in_sizes; (void)n_in; (void)out_size;

    hipMemsetAsync(bcur0, 0, sizeof(int) * NBUCK, stream);

    // fused prep (padded-bucket fill FIRST for overlap, then cvt + gstart + pack_w)
    k_prep<<<PREP_BLOCKS, 256, 0, stream>>>(x, batch, src, dst, W1a, W1b, W2a, W2b,
                                            X16, gstart, Wpack, bcur0, packed);
    // CSR finalize (self-computed bucket prefix)
    k_csrfine<<<NBUCK, 256, 0, stream>>>(packed, bcur0, offsets, csr_src);

    // layer 1
    k_gather16<<<N_NODES / 4, 256, 0, stream>>>(X16, csr_src, offsets, M);
    k_mlp16<1><<<(N_NODES + 255) / 256, 256, 0, stream>>>(M, Wpack + 0 * 16384, b1a,
                                                          Wpack + 1 * 16384, b1b, H1);
    // layer 2
    k_gather16<<<N_NODES / 4, 256, 0, stream>>>(H1, csr_src, offsets, M2);
    k_mlp16<0><<<(N_NODES + 255) / 256, 256, 0, stream>>>(M2, Wpack + 2 * 16384, b2a,
                                                          Wpack + 3 * 16384, b2b, H2);

    // fused mean-pool + head
    k_pool_head<<<N_GRAPHS, 256, 0, stream>>>(H2, gstart, Wlin, blin, out);
}